// Round 1
// baseline (221.954 us; speedup 1.0000x reference)
//
#include <hip/hip_runtime.h>

// Elementwise clamp: out = min(max(x, lo), hi)
// x: 33,554,432 fp32 (4194304 x 8), clamp_params: [lo, hi] fp32.
// Memory-bound streaming kernel: 256 MiB total traffic -> ~43 us at 6.3 TB/s.

__global__ void __launch_bounds__(256) clamp_kernel(
    const float4* __restrict__ x,
    const float* __restrict__ cp,
    float4* __restrict__ out,
    int n4)
{
    const float lo = cp[0];
    const float hi = cp[1];
    int i = blockIdx.x * blockDim.x + threadIdx.x;
    if (i < n4) {
        float4 v = x[i];
        v.x = fminf(fmaxf(v.x, lo), hi);
        v.y = fminf(fmaxf(v.y, lo), hi);
        v.z = fminf(fmaxf(v.z, lo), hi);
        v.w = fminf(fmaxf(v.w, lo), hi);
        out[i] = v;
    }
}

extern "C" void kernel_launch(void* const* d_in, const int* in_sizes, int n_in,
                              void* d_out, int out_size, void* d_ws, size_t ws_size,
                              hipStream_t stream)
{
    const float4* x = (const float4*)d_in[0];
    const float*  cp = (const float*)d_in[1];
    float4* out = (float4*)d_out;

    const int n = in_sizes[0];          // 33,554,432 fp32 elements
    const int n4 = n / 4;               // 8,388,608 float4s (exact)

    const int block = 256;
    const int grid = (n4 + block - 1) / block;   // 32,768 blocks

    clamp_kernel<<<grid, block, 0, stream>>>(x, cp, out, n4);
}